// Round 5
// baseline (432.492 us; speedup 1.0000x reference)
//
#include <hip/hip_runtime.h>
#include <math.h>

// Shapes (fixed by the problem)
#define B_   4
#define N_   16384
#define M_   4096
#define C1_  128
#define C2_  256
#define H_   256
#define K1_  384   // C1 + C2

#define NC_  8           // three_nn chunks over M
#define MC_  (M_ / NC_)  // 512 knowns per chunk
#define NB_  1024        // GEMM grid blocks (128 * 2 * 4) -> stats partials

typedef unsigned long long u64;
typedef __attribute__((ext_vector_type(8))) short bf16x8;   // 8 bf16 (4 VGPRs)
typedef __attribute__((ext_vector_type(4))) float f32x4;    // mfma acc

__device__ __forceinline__ unsigned short f2bf(float x) {
  unsigned u = __float_as_uint(x);
  return (unsigned short)((u + 0x7FFFu + ((u >> 16) & 1u)) >> 16);  // RNE
}

// Branchless insert of (cd,ci) into lex-sorted top-3 {(d1,i1)<=(d2,i2)<=(d3,i3)}.
// Strict < on d: on d-tie the incumbent (earlier index) stays earlier -> exactly
// jax.lax.top_k stability, bit-identical to the packed-f64 scheme of R2-R4.
// 3x v_cmp_lt_f32 + 10x cndmask/min: ~13 wave-instrs vs ~15 (incl. f64 cmps).
__device__ __forceinline__ void ins3(float cd, int ci,
                                     float& d1, int& i1,
                                     float& d2, int& i2,
                                     float& d3, int& i3) {
  bool p0   = cd < d3;
  float x3d = p0 ? cd : d3;  int x3i = p0 ? ci : i3;
  bool p1   = x3d < d2;
  float nd3 = p1 ? d2 : x3d; int ni3 = p1 ? i2 : x3i;
  float td  = p1 ? x3d : d2; int ti  = p1 ? x3i : i2;
  bool p2   = td < d1;
  d3 = nd3; i3 = ni3;
  d2 = p2 ? d1 : td; i2 = p2 ? i1 : ti;
  d1 = p2 ? td : d1; i1 = p2 ? ti : i1;
}

// ---------------------------------------------------------------------------
// 1) transpose known_feats [B, C2, M] -> kfT [B, M, C2] fp32 (for gathers)
// ---------------------------------------------------------------------------
__global__ __launch_bounds__(256) void k_transpose(const float* __restrict__ kf,
                                                   float* __restrict__ kfT) {
  __shared__ float tile[32][33];
  int b  = blockIdx.z;
  int i0 = blockIdx.x * 32;
  int c0 = blockIdx.y * 32;
  int tx  = threadIdx.x & 31;
  int tyv = threadIdx.x >> 5;
  const float* src = kf + ((size_t)b * C2_ + c0) * M_ + i0;
  #pragma unroll
  for (int r = 0; r < 32; r += 8)
    tile[tyv + r][tx] = src[(size_t)(tyv + r) * M_ + tx];
  __syncthreads();
  float* dst = kfT + ((size_t)b * M_ + i0) * C2_ + c0;
  #pragma unroll
  for (int r = 0; r < 32; r += 8)
    dst[(size_t)(tyv + r) * C2_ + tx] = tile[tx][tyv + r];
}

// ---------------------------------------------------------------------------
// 2a) three_nn partials: fp32 (d,idx) pair top-3 per M-chunk.
//     Distance formula identical to R1-R4 (matches numpy selection).
// ---------------------------------------------------------------------------
__global__ __launch_bounds__(256) void k_three_nn_part(const float* __restrict__ unknown,
                                                       const float* __restrict__ known,
                                                       float* __restrict__ part_d,
                                                       int* __restrict__ part_i) {
  __shared__ float4 sk[MC_];
  int b    = blockIdx.y;
  int ch   = blockIdx.z;
  int base = ch * MC_;
  const float* kb = known + ((size_t)b * M_ + base) * 3;
  for (int i = threadIdx.x; i < MC_; i += 256) {
    float x = kb[3*i+0], y = kb[3*i+1], z = kb[3*i+2];
    sk[i] = make_float4(x, y, z, x*x + y*y + z*z);
  }
  __syncthreads();

  int j = blockIdx.x * 256 + threadIdx.x;
  const float* up = unknown + ((size_t)b * N_ + j) * 3;
  float ux = up[0], uy = up[1], uz = up[2];
  float u2 = ux*ux + uy*uy + uz*uz;

  float d1 = __builtin_inff(), d2 = __builtin_inff(), d3 = __builtin_inff();
  int   i1 = 0, i2 = 0, i3 = 0;
  #pragma unroll 4
  for (int i = 0; i < MC_; ++i) {
    float4 k = sk[i];
    float dt = ux*k.x + uy*k.y + uz*k.z;
    float d  = (u2 + k.w) - 2.0f*dt;           // identical arithmetic to ref path
    ins3(d, base + i, d1, i1, d2, i2, d3, i3);
  }
  size_t o = ((size_t)(ch * B_ + b) * 3) * N_ + j;
  part_d[o] = d1; part_d[o + N_] = d2; part_d[o + 2*(size_t)N_] = d3;
  part_i[o] = i1; part_i[o + N_] = i2; part_i[o + 2*(size_t)N_] = i3;
}

// ---------------------------------------------------------------------------
// 2b) merge NC partial top-3 lists -> final idx + inverse-distance weights.
//     Chunks merged in ascending order; within-chunk triples are lex-sorted,
//     so incumbent-wins tie-breaking == global lower-index-wins (exact).
// ---------------------------------------------------------------------------
__global__ __launch_bounds__(256) void k_three_merge(const float* __restrict__ part_d,
                                                     const int* __restrict__ part_i,
                                                     int* __restrict__ idx_o,
                                                     float* __restrict__ w_o) {
  int j = blockIdx.x * 256 + threadIdx.x;
  int b = blockIdx.y;
  size_t o0 = ((size_t)b * 3) * N_ + j;
  float d1 = part_d[o0], d2 = part_d[o0 + N_], d3 = part_d[o0 + 2*(size_t)N_];
  int   i1 = part_i[o0], i2 = part_i[o0 + N_], i3 = part_i[o0 + 2*(size_t)N_];
  #pragma unroll
  for (int c = 1; c < NC_; ++c) {
    size_t oc = ((size_t)(c * B_ + b) * 3) * N_ + j;
    #pragma unroll
    for (int k = 0; k < 3; ++k) {
      float cd = part_d[oc + (size_t)k * N_];
      int   ci = part_i[oc + (size_t)k * N_];
      ins3(cd, ci, d1, i1, d2, i2, d3, i3);
    }
  }
  float r1 = 1.0f / (d1 + 1e-8f);
  float r2 = 1.0f / (d2 + 1e-8f);
  float r3 = 1.0f / (d3 + 1e-8f);
  float s  = r1 + r2 + r3;
  size_t o = ((size_t)b * N_ + j) * 3;
  idx_o[o+0] = i1; idx_o[o+1] = i2; idx_o[o+2] = i3;
  w_o[o+0] = r1 / s; w_o[o+1] = r2 / s; w_o[o+2] = r3 / s;
}

// ---------------------------------------------------------------------------
// 3a) three_interpolate -> Xb1[b][j][0:256] bf16 (point-major GEMM operand)
// ---------------------------------------------------------------------------
#define IP_ 32
__global__ __launch_bounds__(256) void k_interp(const float* __restrict__ kfT,
                                                const int* __restrict__ idx,
                                                const float* __restrict__ wgt,
                                                unsigned short* __restrict__ Xb1) {
  int b  = blockIdx.y;
  int j0 = blockIdx.x * IP_;
  const float* kb = kfT + (size_t)b * M_ * C2_;
  int c = threadIdx.x;
  for (int p = 0; p < IP_; ++p) {
    size_t pj = ((size_t)b * N_ + j0 + p) * 3;   // uniform -> scalar loads
    int   i0 = idx[pj+0], i1 = idx[pj+1], i2 = idx[pj+2];
    float w0 = wgt[pj+0], w1 = wgt[pj+1], w2 = wgt[pj+2];
    float v = w0 * kb[(size_t)i0 * C2_ + c]
            + w1 * kb[(size_t)i1 * C2_ + c]
            + w2 * kb[(size_t)i2 * C2_ + c];
    Xb1[((size_t)b * N_ + j0 + p) * K1_ + c] = f2bf(v);
  }
}

// ---------------------------------------------------------------------------
// 3b) transpose+cast unknown_feats [B,C1,N] fp32 -> Xb1[b][j][256+c] bf16
// ---------------------------------------------------------------------------
__global__ __launch_bounds__(256) void k_uf_t(const float* __restrict__ uf,
                                              unsigned short* __restrict__ Xb1) {
  __shared__ float tile[32][33];
  int b  = blockIdx.z;
  int j0 = blockIdx.x * 32;
  int c0 = blockIdx.y * 32;
  int tx = threadIdx.x & 31, ty = threadIdx.x >> 5;
  const float* src = uf + ((size_t)b * C1_ + c0) * N_ + j0;
  #pragma unroll
  for (int r = 0; r < 32; r += 8)
    tile[ty + r][tx] = src[(size_t)(ty + r) * N_ + tx];
  __syncthreads();
  unsigned short* dst = Xb1 + ((size_t)b * N_ + j0) * K1_ + C2_ + c0;
  #pragma unroll
  for (int r = 0; r < 32; r += 8)
    dst[(size_t)(ty + r) * K1_ + tx] = f2bf(tile[tx][ty + r]);
}

// ---------------------------------------------------------------------------
// 3c) cast weights to bf16 (row-major unchanged)
// ---------------------------------------------------------------------------
__global__ void k_wcast(const float* __restrict__ W, unsigned short* __restrict__ Wb, int n) {
  int i = blockIdx.x * 256 + threadIdx.x;
  if (i < n) Wb[i] = f2bf(W[i]);
}

// ---------------------------------------------------------------------------
// 4) bf16 MFMA GEMM, NO LDS staging, NO K-loop barriers (R4 structure).
// ---------------------------------------------------------------------------
template <int K, int OUTL>
__global__ __launch_bounds__(256) void k_gemm_mfma(const unsigned short* __restrict__ Wb,
                                                   const unsigned short* __restrict__ Xb,
                                                   float* __restrict__ outp,
                                                   float* __restrict__ stats_p) {
  __shared__ float sred[256];     // [0:128) sum, [128:256) sumsq for this m-tile
  int t = threadIdx.x;
  sred[t] = 0.0f;
  __syncthreads();

  int b  = blockIdx.z;
  int m0 = blockIdx.y * 128;
  int j0 = blockIdx.x * 128;
  int wid = t >> 6, lane = t & 63;
  int wr = wid >> 1, wc = wid & 1;          // wave quadrant (m, n)
  int l15 = lane & 15, quad = lane >> 4;

  const unsigned short* aptr = Wb + (size_t)(m0 + 64*wr + l15) * K + quad * 8;
  const unsigned short* bptr = Xb + ((size_t)b * N_ + j0 + 64*wc + l15) * K + quad * 8;

  f32x4 acc[4][4] = {};
  for (int kt = 0; kt < K; kt += 32) {
    bf16x8 af[4], bfr[4];
    #pragma unroll
    for (int i = 0; i < 4; ++i)
      af[i] = *(const bf16x8*)(aptr + (size_t)(16*i) * K + kt);
    #pragma unroll
    for (int i = 0; i < 4; ++i)
      bfr[i] = *(const bf16x8*)(bptr + (size_t)(16*i) * K + kt);
    #pragma unroll
    for (int im = 0; im < 4; ++im)
      #pragma unroll
      for (int in = 0; in < 4; ++in)
        acc[im][in] = __builtin_amdgcn_mfma_f32_16x16x32_bf16(af[im], bfr[in], acc[im][in], 0, 0, 0);
  }

  // --- BN statistics: shuffle-reduce over 16 n-lanes, combine in LDS ---
  #pragma unroll
  for (int im = 0; im < 4; ++im) {
    #pragma unroll
    for (int r = 0; r < 4; ++r) {
      float sv = 0.f, qv = 0.f;
      #pragma unroll
      for (int in = 0; in < 4; ++in) { float v = acc[im][in][r]; sv += v; qv += v * v; }
      #pragma unroll
      for (int off = 1; off < 16; off <<= 1) {
        sv += __shfl_xor(sv, off, 64);
        qv += __shfl_xor(qv, off, 64);
      }
      if (l15 == 0) {
        int ml = 64*wr + 16*im + 4*quad + r;   // 0..127 within tile
        atomicAdd(&sred[ml], sv);              // LDS atomic, 2-way at most
        atomicAdd(&sred[128 + ml], qv);
      }
    }
  }
  __syncthreads();
  if (t < 128) {
    int bid = (blockIdx.z * gridDim.y + blockIdx.y) * gridDim.x + blockIdx.x;
    stats_p[(size_t)(m0 + t) * NB_ + bid]       = sred[t];
    stats_p[(size_t)(256 + m0 + t) * NB_ + bid] = sred[128 + t];
  }

  // --- store ---
  if (OUTL == 0) {
    #pragma unroll
    for (int in = 0; in < 4; ++in) {
      size_t nrow = (size_t)b * N_ + j0 + 64*wc + 16*in + l15;
      float* p = outp + nrow * 256 + m0 + 64*wr + quad * 4;
      #pragma unroll
      for (int im = 0; im < 4; ++im)
        *(f32x4*)(p + 16 * im) = acc[im][in];
    }
  } else {
    #pragma unroll
    for (int im = 0; im < 4; ++im)
      #pragma unroll
      for (int r = 0; r < 4; ++r) {
        int m = m0 + 64*wr + 16*im + 4*quad + r;
        size_t base = ((size_t)b * 256 + m) * N_ + j0 + 64*wc + l15;
        #pragma unroll
        for (int in = 0; in < 4; ++in)
          outp[base + 16 * in] = acc[im][in][r];
      }
  }
}

// ---------------------------------------------------------------------------
// 5) reduce per-block stats partials -> bnp (scale/shift). One block per channel.
// ---------------------------------------------------------------------------
__global__ __launch_bounds__(256) void k_reduce_bn(const float* __restrict__ sp,
                                                   const float* __restrict__ gamma,
                                                   const float* __restrict__ beta,
                                                   float* __restrict__ bnp) {
  int c = blockIdx.x;        // 0..255
  int t = threadIdx.x;
  float s = 0.f, q = 0.f;
  for (int i = t; i < NB_; i += 256) {
    s += sp[(size_t)c * NB_ + i];
    q += sp[(size_t)(256 + c) * NB_ + i];
  }
  #pragma unroll
  for (int off = 32; off >= 1; off >>= 1) {
    s += __shfl_down(s, off, 64);
    q += __shfl_down(q, off, 64);
  }
  __shared__ float ss[4], qq[4];
  if ((t & 63) == 0) { ss[t >> 6] = s; qq[t >> 6] = q; }
  __syncthreads();
  if (t == 0) {
    s = ss[0] + ss[1] + ss[2] + ss[3];
    q = qq[0] + qq[1] + qq[2] + qq[3];
    const float inv = 1.0f / (float)(B_ * N_);
    float mean = s * inv;
    float var  = q * inv - mean * mean;
    float sc = gamma[c] / sqrtf(var + 1e-5f);
    bnp[c] = sc;
    bnp[256 + c] = beta[c] - mean * sc;
  }
}

// ---------------------------------------------------------------------------
// 6) bn1 + relu + cast: h[b][n][256] fp32 -> Xb2[b][n][256] bf16
// ---------------------------------------------------------------------------
__global__ __launch_bounds__(256) void k_bn_relu_cast(const float* __restrict__ h,
                                                      const float* __restrict__ bnp,
                                                      unsigned short* __restrict__ Xb2) {
  size_t e = (size_t)blockIdx.x * 256 + threadIdx.x;   // float4 index
  float4 v = ((const float4*)h)[e];
  int c0 = (int)((e & 63) << 2);                       // 64 float4 per point-row
  float4 sc = *(const float4*)(bnp + c0);
  float4 sh = *(const float4*)(bnp + 256 + c0);
  ushort4 o;
  o.x = f2bf(fmaxf(fmaf(sc.x, v.x, sh.x), 0.0f));
  o.y = f2bf(fmaxf(fmaf(sc.y, v.y, sh.y), 0.0f));
  o.z = f2bf(fmaxf(fmaf(sc.z, v.z, sh.z), 0.0f));
  o.w = f2bf(fmaxf(fmaf(sc.w, v.w, sh.w), 0.0f));
  ((ushort4*)Xb2)[e] = o;
}

// ---------------------------------------------------------------------------
// 7) final BN + ReLU in place on d_out [B][H][N]
// ---------------------------------------------------------------------------
__global__ __launch_bounds__(256) void k_bn_relu(float* __restrict__ out,
                                                 const float* __restrict__ bnp) {
  size_t e = (size_t)blockIdx.x * 256 + threadIdx.x;
  float4 v = ((float4*)out)[e];
  int c = (int)((e >> 12) & 255);
  float sc = bnp[c], sh = bnp[256 + c];
  v.x = fmaxf(fmaf(sc, v.x, sh), 0.0f);
  v.y = fmaxf(fmaf(sc, v.y, sh), 0.0f);
  v.z = fmaxf(fmaf(sc, v.z, sh), 0.0f);
  v.w = fmaxf(fmaf(sc, v.w, sh), 0.0f);
  ((float4*)out)[e] = v;
}

// ---------------------------------------------------------------------------
extern "C" void kernel_launch(void* const* d_in, const int* in_sizes, int n_in,
                              void* d_out, int out_size, void* d_ws, size_t ws_size,
                              hipStream_t stream) {
  const float* unknown = (const float*)d_in[0];
  const float* known   = (const float*)d_in[1];
  const float* uf      = (const float*)d_in[2];
  const float* kf      = (const float*)d_in[3];
  const float* W1      = (const float*)d_in[4];
  const float* g1      = (const float*)d_in[5];
  const float* b1      = (const float*)d_in[6];
  const float* W2      = (const float*)d_in[7];
  const float* g2      = (const float*)d_in[8];
  const float* b2      = (const float*)d_in[9];
  float* out = (float*)d_out;

  // workspace layout (~71 MB):
  //   kfT     : B*M*C2 fp32 = 16.8 MB
  //   Xb1     : B*N*K1 bf16 = 48 MB   (alias: part_d/part_i early, Xb2 late)
  //   idx/wgt : 1.6 MB ; W1b/W2b : 0.33 MB ; stats_p : 2 MB
  // h (B*N*H fp32, 64 MB) lives in d_out until GEMM2 overwrites it.
  float* ws = (float*)d_ws;
  float*          kfT  = ws;                                          // 4194304 f
  unsigned short* Xb1  = (unsigned short*)(kfT + (size_t)B_*M_*C2_);  // 25165824 us
  float*          part_d = (float*)Xb1;                               // alias (early)
  int*            part_i = (int*)(part_d + (size_t)NC_*B_*3*N_);      // 6.3 MB each
  unsigned short* Xb2  = Xb1;                                         // alias (late)
  int*   idx    = (int*)(Xb1 + (size_t)B_*N_*K1_);
  float* wgt    = (float*)(idx + (size_t)B_*N_*3);
  unsigned short* W1b = (unsigned short*)(wgt + (size_t)B_*N_*3);     // 98304 us
  unsigned short* W2b = W1b + H_*K1_;                                 // 65536 us
  float* stats_p = (float*)(W2b + H_*H_);                             // 524288 f
  float* bnp1   = stats_p + 512 * NB_;
  float* bnp2   = bnp1 + 512;
  float* h      = out;                                                // d_out scratch

  k_wcast<<<(H_*K1_ + 255)/256, 256, 0, stream>>>(W1, W1b, H_*K1_);
  k_wcast<<<(H_*H_  + 255)/256, 256, 0, stream>>>(W2, W2b, H_*H_);
  k_transpose<<<dim3(M_/32, C2_/32, B_), 256, 0, stream>>>(kf, kfT);
  k_three_nn_part<<<dim3(N_/256, B_, NC_), 256, 0, stream>>>(unknown, known, part_d, part_i);
  k_three_merge<<<dim3(N_/256, B_), 256, 0, stream>>>(part_d, part_i, idx, wgt);
  k_interp<<<dim3(N_/IP_, B_), 256, 0, stream>>>(kfT, idx, wgt, Xb1);
  k_uf_t<<<dim3(N_/32, C1_/32, B_), 256, 0, stream>>>(uf, Xb1);
  k_gemm_mfma<K1_, 0><<<dim3(N_/128, 2, B_), 256, 0, stream>>>(W1b, Xb1, h, stats_p);
  k_reduce_bn<<<256, 256, 0, stream>>>(stats_p, g1, b1, bnp1);
  k_bn_relu_cast<<<(int)((size_t)B_*N_*H_/4/256), 256, 0, stream>>>(h, bnp1, Xb2);
  k_gemm_mfma<H_, 1><<<dim3(N_/128, 2, B_), 256, 0, stream>>>(W2b, Xb2, out, stats_p);
  k_reduce_bn<<<256, 256, 0, stream>>>(stats_p, g2, b2, bnp2);
  k_bn_relu<<<(int)((size_t)B_*H_*N_/4/256), 256, 0, stream>>>(out, bnp2);
}

// Round 6
// 387.808 us; speedup vs baseline: 1.1152x; 1.1152x over previous
//
#include <hip/hip_runtime.h>
#include <math.h>

// Shapes (fixed by the problem)
#define B_   4
#define N_   16384
#define M_   4096
#define C1_  128
#define C2_  256
#define H_   256
#define K1_  384   // C1 + C2

#define NC_  8           // three_nn chunks over M
#define MC_  (M_ / NC_)  // 512 knowns per chunk
#define NB_  1024        // GEMM grid blocks (128 * 2 * 4) -> stats partials

typedef unsigned long long u64;
typedef __attribute__((ext_vector_type(8))) short bf16x8;   // 8 bf16 (4 VGPRs)
typedef __attribute__((ext_vector_type(4))) float f32x4;    // mfma acc

__device__ __forceinline__ unsigned short f2bf(float x) {
  unsigned u = __float_as_uint(x);
  return (unsigned short)((u + 0x7FFFu + ((u >> 16) & 1u)) >> 16);  // RNE
}
__device__ __forceinline__ float bf2f(unsigned short u) {
  return __uint_as_float((unsigned)u << 16);
}

// fp32-pair branchless insert (used only in the tiny merge kernel)
__device__ __forceinline__ void ins3(float cd, int ci,
                                     float& d1, int& i1,
                                     float& d2, int& i2,
                                     float& d3, int& i3) {
  bool p3 = cd < d3, p2 = cd < d2, p1 = cd < d1;
  float td = p1 ? d1 : cd; int ti = p1 ? i1 : ci;
  d1 = p1 ? cd : d1;       i1 = p1 ? ci : i1;
  float e3 = p2 ? d2 : cd; int e3i = p2 ? i2 : ci;
  d2 = p2 ? td : d2;       i2 = p2 ? ti : i2;
  d3 = p3 ? e3 : d3;       i3 = p3 ? e3i : i3;
}

// ---------------------------------------------------------------------------
// 1) transpose known_feats [B, C2, M] -> kfT [B, M, C2] fp32 (for gathers)
// ---------------------------------------------------------------------------
__global__ __launch_bounds__(256) void k_transpose(const float* __restrict__ kf,
                                                   float* __restrict__ kfT) {
  __shared__ float tile[32][33];
  int b  = blockIdx.z;
  int i0 = blockIdx.x * 32;
  int c0 = blockIdx.y * 32;
  int tx  = threadIdx.x & 31;
  int tyv = threadIdx.x >> 5;
  const float* src = kf + ((size_t)b * C2_ + c0) * M_ + i0;
  #pragma unroll
  for (int r = 0; r < 32; r += 8)
    tile[tyv + r][tx] = src[(size_t)(tyv + r) * M_ + tx];
  __syncthreads();
  float* dst = kfT + ((size_t)b * M_ + i0) * C2_ + c0;
  #pragma unroll
  for (int r = 0; r < 32; r += 8)
    dst[(size_t)(tyv + r) * C2_ + tx] = tile[tx][tyv + r];
}

// ---------------------------------------------------------------------------
// 2a) three_nn partials. Hot loop: 3-FMA score + 1 compare; the insert network
//     runs only under a wave-uniform __any branch (rare after warm-up).
//     LDS holds (-2x, -2y, -2z, k^2); s = k^2 - 2*dot; d = u^2 + s (±2ulp of
//     the reference formula -- set-flips only at sub-ulp d3/d4 gaps, harmless).
//     Strict < keeps lower index on ties (ascending scan == top_k stability).
// ---------------------------------------------------------------------------
__global__ __launch_bounds__(256) void k_three_nn_part(const float* __restrict__ unknown,
                                                       const float* __restrict__ known,
                                                       float* __restrict__ part_d,
                                                       int* __restrict__ part_i) {
  __shared__ float4 sk[MC_];
  int b    = blockIdx.y;
  int ch   = blockIdx.z;
  int base = ch * MC_;
  const float* kb = known + ((size_t)b * M_ + base) * 3;
  for (int i = threadIdx.x; i < MC_; i += 256) {
    float x = kb[3*i+0], y = kb[3*i+1], z = kb[3*i+2];
    sk[i] = make_float4(-2.0f*x, -2.0f*y, -2.0f*z, x*x + y*y + z*z);
  }
  __syncthreads();

  int j = blockIdx.x * 256 + threadIdx.x;
  const float* up = unknown + ((size_t)b * N_ + j) * 3;
  float ux = up[0], uy = up[1], uz = up[2];
  float u2 = ux*ux + uy*uy + uz*uz;

  const float INF = __builtin_inff();
  float d1 = INF, d2 = INF, d3 = INF, t3 = INF;
  int   i1 = 0, i2 = 0, i3 = 0;
  #pragma unroll 4
  for (int i = 0; i < MC_; ++i) {
    float4 k = sk[i];
    float s = fmaf(k.x, ux, fmaf(k.y, uy, fmaf(k.z, uz, k.w)));  // k2 - 2*dot
    if (__any(s < t3)) {
      float d = u2 + s;
      int  gi = base + i;
      bool p3 = d < d3, p2 = d < d2, p1 = d < d1;
      float td = p1 ? d1 : d; int ti = p1 ? i1 : gi;
      d1 = p1 ? d : d1;       i1 = p1 ? gi : i1;
      float e3 = p2 ? d2 : d; int e3i = p2 ? i2 : gi;
      d2 = p2 ? td : d2;      i2 = p2 ? ti : i2;
      d3 = p3 ? e3 : d3;      i3 = p3 ? e3i : i3;
      t3 = d3 - u2;
    }
  }
  size_t o = ((size_t)(ch * B_ + b) * 3) * N_ + j;
  part_d[o] = d1; part_d[o + N_] = d2; part_d[o + 2*(size_t)N_] = d3;
  part_i[o] = i1; part_i[o + N_] = i2; part_i[o + 2*(size_t)N_] = i3;
}

// ---------------------------------------------------------------------------
// 2b) merge NC partial top-3 lists -> final idx + inverse-distance weights.
// ---------------------------------------------------------------------------
__global__ __launch_bounds__(256) void k_three_merge(const float* __restrict__ part_d,
                                                     const int* __restrict__ part_i,
                                                     int* __restrict__ idx_o,
                                                     float* __restrict__ w_o) {
  int j = blockIdx.x * 256 + threadIdx.x;
  int b = blockIdx.y;
  size_t o0 = ((size_t)b * 3) * N_ + j;
  float d1 = part_d[o0], d2 = part_d[o0 + N_], d3 = part_d[o0 + 2*(size_t)N_];
  int   i1 = part_i[o0], i2 = part_i[o0 + N_], i3 = part_i[o0 + 2*(size_t)N_];
  #pragma unroll
  for (int c = 1; c < NC_; ++c) {
    size_t oc = ((size_t)(c * B_ + b) * 3) * N_ + j;
    #pragma unroll
    for (int k = 0; k < 3; ++k) {
      float cd = part_d[oc + (size_t)k * N_];
      int   ci = part_i[oc + (size_t)k * N_];
      ins3(cd, ci, d1, i1, d2, i2, d3, i3);
    }
  }
  float r1 = 1.0f / (d1 + 1e-8f);
  float r2 = 1.0f / (d2 + 1e-8f);
  float r3 = 1.0f / (d3 + 1e-8f);
  float s  = r1 + r2 + r3;
  size_t o = ((size_t)b * N_ + j) * 3;
  idx_o[o+0] = i1; idx_o[o+1] = i2; idx_o[o+2] = i3;
  w_o[o+0] = r1 / s; w_o[o+1] = r2 / s; w_o[o+2] = r3 / s;
}

// ---------------------------------------------------------------------------
// 3a) three_interpolate -> Xb1[b][j][0:256] bf16 (point-major GEMM operand)
// ---------------------------------------------------------------------------
#define IP_ 32
__global__ __launch_bounds__(256) void k_interp(const float* __restrict__ kfT,
                                                const int* __restrict__ idx,
                                                const float* __restrict__ wgt,
                                                unsigned short* __restrict__ Xb1) {
  int b  = blockIdx.y;
  int j0 = blockIdx.x * IP_;
  const float* kb = kfT + (size_t)b * M_ * C2_;
  int c = threadIdx.x;
  for (int p = 0; p < IP_; ++p) {
    size_t pj = ((size_t)b * N_ + j0 + p) * 3;   // uniform -> scalar loads
    int   i0 = idx[pj+0], i1 = idx[pj+1], i2 = idx[pj+2];
    float w0 = wgt[pj+0], w1 = wgt[pj+1], w2 = wgt[pj+2];
    float v = w0 * kb[(size_t)i0 * C2_ + c]
            + w1 * kb[(size_t)i1 * C2_ + c]
            + w2 * kb[(size_t)i2 * C2_ + c];
    Xb1[((size_t)b * N_ + j0 + p) * K1_ + c] = f2bf(v);
  }
}

// ---------------------------------------------------------------------------
// 3b) transpose+cast unknown_feats [B,C1,N] fp32 -> Xb1[b][j][256+c] bf16
// ---------------------------------------------------------------------------
__global__ __launch_bounds__(256) void k_uf_t(const float* __restrict__ uf,
                                              unsigned short* __restrict__ Xb1) {
  __shared__ float tile[32][33];
  int b  = blockIdx.z;
  int j0 = blockIdx.x * 32;
  int c0 = blockIdx.y * 32;
  int tx = threadIdx.x & 31, ty = threadIdx.x >> 5;
  const float* src = uf + ((size_t)b * C1_ + c0) * N_ + j0;
  #pragma unroll
  for (int r = 0; r < 32; r += 8)
    tile[ty + r][tx] = src[(size_t)(ty + r) * N_ + tx];
  __syncthreads();
  unsigned short* dst = Xb1 + ((size_t)b * N_ + j0) * K1_ + C2_ + c0;
  #pragma unroll
  for (int r = 0; r < 32; r += 8)
    dst[(size_t)(ty + r) * K1_ + tx] = f2bf(tile[tx][ty + r]);
}

// ---------------------------------------------------------------------------
// 3c) cast both weight matrices to bf16 (fused, contiguous dst)
// ---------------------------------------------------------------------------
__global__ void k_wcast(const float* __restrict__ W1, const float* __restrict__ W2,
                        unsigned short* __restrict__ Wb) {
  int i = blockIdx.x * 256 + threadIdx.x;
  int n1 = H_ * K1_, nt = n1 + H_ * H_;
  if (i < nt) Wb[i] = f2bf(i < n1 ? W1[i] : W2[i - n1]);
}

// ---------------------------------------------------------------------------
// 4) bf16 MFMA GEMM, NO LDS staging, NO K-loop barriers (R4 structure).
//    OUTL 0: write h[b][n][m] bf16 (point-major, feeds bn_relu_cast)
//    OUTL 1: write out[b][m][n] fp32 (final layout)
// ---------------------------------------------------------------------------
template <int K, int OUTL>
__global__ __launch_bounds__(256) void k_gemm_mfma(const unsigned short* __restrict__ Wb,
                                                   const unsigned short* __restrict__ Xb,
                                                   float* __restrict__ outp,
                                                   float* __restrict__ stats_p) {
  __shared__ float sred[256];     // [0:128) sum, [128:256) sumsq for this m-tile
  int t = threadIdx.x;
  sred[t] = 0.0f;
  __syncthreads();

  int b  = blockIdx.z;
  int m0 = blockIdx.y * 128;
  int j0 = blockIdx.x * 128;
  int wid = t >> 6, lane = t & 63;
  int wr = wid >> 1, wc = wid & 1;          // wave quadrant (m, n)
  int l15 = lane & 15, quad = lane >> 4;

  const unsigned short* aptr = Wb + (size_t)(m0 + 64*wr + l15) * K + quad * 8;
  const unsigned short* bptr = Xb + ((size_t)b * N_ + j0 + 64*wc + l15) * K + quad * 8;

  f32x4 acc[4][4] = {};
  for (int kt = 0; kt < K; kt += 32) {
    bf16x8 af[4], bfr[4];
    #pragma unroll
    for (int i = 0; i < 4; ++i)
      af[i] = *(const bf16x8*)(aptr + (size_t)(16*i) * K + kt);
    #pragma unroll
    for (int i = 0; i < 4; ++i)
      bfr[i] = *(const bf16x8*)(bptr + (size_t)(16*i) * K + kt);
    #pragma unroll
    for (int im = 0; im < 4; ++im)
      #pragma unroll
      for (int in = 0; in < 4; ++in)
        acc[im][in] = __builtin_amdgcn_mfma_f32_16x16x32_bf16(af[im], bfr[in], acc[im][in], 0, 0, 0);
  }

  // --- BN statistics: shuffle-reduce over 16 n-lanes, combine in LDS ---
  #pragma unroll
  for (int im = 0; im < 4; ++im) {
    #pragma unroll
    for (int r = 0; r < 4; ++r) {
      float sv = 0.f, qv = 0.f;
      #pragma unroll
      for (int in = 0; in < 4; ++in) { float v = acc[im][in][r]; sv += v; qv += v * v; }
      #pragma unroll
      for (int off = 1; off < 16; off <<= 1) {
        sv += __shfl_xor(sv, off, 64);
        qv += __shfl_xor(qv, off, 64);
      }
      if (l15 == 0) {
        int ml = 64*wr + 16*im + 4*quad + r;   // 0..127 within tile
        atomicAdd(&sred[ml], sv);              // LDS atomic, 2-way at most
        atomicAdd(&sred[128 + ml], qv);
      }
    }
  }
  __syncthreads();
  if (t < 128) {
    int bid = (blockIdx.z * gridDim.y + blockIdx.y) * gridDim.x + blockIdx.x;
    stats_p[(size_t)(m0 + t) * NB_ + bid]       = sred[t];
    stats_p[(size_t)(256 + m0 + t) * NB_ + bid] = sred[128 + t];
  }

  // --- store ---
  if (OUTL == 0) {
    unsigned short* hp = (unsigned short*)outp;   // h bf16 [b][n][256]
    #pragma unroll
    for (int in = 0; in < 4; ++in) {
      size_t nrow = (size_t)b * N_ + j0 + 64*wc + 16*in + l15;
      unsigned short* p = hp + nrow * 256 + m0 + 64*wr + quad * 4;
      #pragma unroll
      for (int im = 0; im < 4; ++im) {
        ushort4 o;
        o.x = f2bf(acc[im][in][0]); o.y = f2bf(acc[im][in][1]);
        o.z = f2bf(acc[im][in][2]); o.w = f2bf(acc[im][in][3]);
        *(ushort4*)(p + 16 * im) = o;
      }
    }
  } else {
    #pragma unroll
    for (int im = 0; im < 4; ++im)
      #pragma unroll
      for (int r = 0; r < 4; ++r) {
        int m = m0 + 64*wr + 16*im + 4*quad + r;
        size_t base = ((size_t)b * 256 + m) * N_ + j0 + 64*wc + l15;
        #pragma unroll
        for (int in = 0; in < 4; ++in)
          outp[base + 16 * in] = acc[im][in][r];
      }
  }
}

// ---------------------------------------------------------------------------
// 5) reduce per-block stats partials -> bnp (scale/shift). One block per channel.
// ---------------------------------------------------------------------------
__global__ __launch_bounds__(256) void k_reduce_bn(const float* __restrict__ sp,
                                                   const float* __restrict__ gamma,
                                                   const float* __restrict__ beta,
                                                   float* __restrict__ bnp) {
  int c = blockIdx.x;        // 0..255
  int t = threadIdx.x;
  float s = 0.f, q = 0.f;
  for (int i = t; i < NB_; i += 256) {
    s += sp[(size_t)c * NB_ + i];
    q += sp[(size_t)(256 + c) * NB_ + i];
  }
  #pragma unroll
  for (int off = 32; off >= 1; off >>= 1) {
    s += __shfl_down(s, off, 64);
    q += __shfl_down(q, off, 64);
  }
  __shared__ float ss[4], qq[4];
  if ((t & 63) == 0) { ss[t >> 6] = s; qq[t >> 6] = q; }
  __syncthreads();
  if (t == 0) {
    s = ss[0] + ss[1] + ss[2] + ss[3];
    q = qq[0] + qq[1] + qq[2] + qq[3];
    const float inv = 1.0f / (float)(B_ * N_);
    float mean = s * inv;
    float var  = q * inv - mean * mean;
    float sc = gamma[c] / sqrtf(var + 1e-5f);
    bnp[c] = sc;
    bnp[256 + c] = beta[c] - mean * sc;
  }
}

// ---------------------------------------------------------------------------
// 6) bn1 + relu: h[b][n][256] bf16 -> Xb2[b][n][256] bf16
// ---------------------------------------------------------------------------
__global__ __launch_bounds__(256) void k_bn_relu_cast(const unsigned short* __restrict__ h,
                                                      const float* __restrict__ bnp,
                                                      unsigned short* __restrict__ Xb2) {
  size_t e = (size_t)blockIdx.x * 256 + threadIdx.x;   // ushort4 index
  ushort4 v = ((const ushort4*)h)[e];
  int c0 = (int)((e & 63) << 2);                       // 64 ushort4 per point-row
  float4 sc = *(const float4*)(bnp + c0);
  float4 sh = *(const float4*)(bnp + 256 + c0);
  ushort4 o;
  o.x = f2bf(fmaxf(fmaf(sc.x, bf2f(v.x), sh.x), 0.0f));
  o.y = f2bf(fmaxf(fmaf(sc.y, bf2f(v.y), sh.y), 0.0f));
  o.z = f2bf(fmaxf(fmaf(sc.z, bf2f(v.z), sh.z), 0.0f));
  o.w = f2bf(fmaxf(fmaf(sc.w, bf2f(v.w), sh.w), 0.0f));
  ((ushort4*)Xb2)[e] = o;
}

// ---------------------------------------------------------------------------
// 7) final BN + ReLU in place on d_out [B][H][N]
// ---------------------------------------------------------------------------
__global__ __launch_bounds__(256) void k_bn_relu(float* __restrict__ out,
                                                 const float* __restrict__ bnp) {
  size_t e = (size_t)blockIdx.x * 256 + threadIdx.x;
  float4 v = ((float4*)out)[e];
  int c = (int)((e >> 12) & 255);
  float sc = bnp[c], sh = bnp[256 + c];
  v.x = fmaxf(fmaf(sc, v.x, sh), 0.0f);
  v.y = fmaxf(fmaf(sc, v.y, sh), 0.0f);
  v.z = fmaxf(fmaf(sc, v.z, sh), 0.0f);
  v.w = fmaxf(fmaf(sc, v.w, sh), 0.0f);
  ((float4*)out)[e] = v;
}

// ---------------------------------------------------------------------------
extern "C" void kernel_launch(void* const* d_in, const int* in_sizes, int n_in,
                              void* d_out, int out_size, void* d_ws, size_t ws_size,
                              hipStream_t stream) {
  const float* unknown = (const float*)d_in[0];
  const float* known   = (const float*)d_in[1];
  const float* uf      = (const float*)d_in[2];
  const float* kf      = (const float*)d_in[3];
  const float* W1      = (const float*)d_in[4];
  const float* g1      = (const float*)d_in[5];
  const float* b1      = (const float*)d_in[6];
  const float* W2      = (const float*)d_in[7];
  const float* g2      = (const float*)d_in[8];
  const float* b2      = (const float*)d_in[9];
  float* out = (float*)d_out;

  // workspace layout (~71 MB):
  //   kfT     : B*M*C2 fp32 = 16.8 MB
  //   Xb1     : B*N*K1 bf16 = 48 MB   (alias: part_d/part_i early, Xb2 late)
  //   idx/wgt : 1.6 MB ; Wb : 0.33 MB ; stats_p : 2 MB
  // h (B*N*H bf16, 32 MB) lives in d_out until GEMM2 overwrites it.
  float* ws = (float*)d_ws;
  float*          kfT  = ws;                                          // 4194304 f
  unsigned short* Xb1  = (unsigned short*)(kfT + (size_t)B_*M_*C2_);  // 25165824 us
  float*          part_d = (float*)Xb1;                               // alias (early)
  int*            part_i = (int*)(part_d + (size_t)NC_*B_*3*N_);      // 6.3 MB each
  unsigned short* Xb2  = Xb1;                                         // alias (late)
  int*   idx    = (int*)(Xb1 + (size_t)B_*N_*K1_);
  float* wgt    = (float*)(idx + (size_t)B_*N_*3);
  unsigned short* W1b = (unsigned short*)(wgt + (size_t)B_*N_*3);     // 98304 us
  unsigned short* W2b = W1b + H_*K1_;                                 // 65536 us
  float* stats_p = (float*)(W2b + H_*H_);                             // 524288 f
  float* bnp1   = stats_p + 512 * NB_;
  float* bnp2   = bnp1 + 512;
  float* h      = out;                                                // d_out scratch (bf16)

  k_wcast<<<(H_*K1_ + H_*H_ + 255)/256, 256, 0, stream>>>(W1, W2, W1b);
  k_transpose<<<dim3(M_/32, C2_/32, B_), 256, 0, stream>>>(kf, kfT);
  k_three_nn_part<<<dim3(N_/256, B_, NC_), 256, 0, stream>>>(unknown, known, part_d, part_i);
  k_three_merge<<<dim3(N_/256, B_), 256, 0, stream>>>(part_d, part_i, idx, wgt);
  k_interp<<<dim3(N_/IP_, B_), 256, 0, stream>>>(kfT, idx, wgt, Xb1);
  k_uf_t<<<dim3(N_/32, C1_/32, B_), 256, 0, stream>>>(uf, Xb1);
  k_gemm_mfma<K1_, 0><<<dim3(N_/128, 2, B_), 256, 0, stream>>>(W1b, Xb1, h, stats_p);
  k_reduce_bn<<<256, 256, 0, stream>>>(stats_p, g1, b1, bnp1);
  k_bn_relu_cast<<<(int)((size_t)B_*N_*H_/4/256), 256, 0, stream>>>((unsigned short*)h, bnp1, Xb2);
  k_gemm_mfma<H_, 1><<<dim3(N_/128, 2, B_), 256, 0, stream>>>(W2b, Xb2, out, stats_p);
  k_reduce_bn<<<256, 256, 0, stream>>>(stats_p, g2, b2, bnp2);
  k_bn_relu<<<(int)((size_t)B_*H_*N_/4/256), 256, 0, stream>>>(out, bnp2);
}